// Round 5
// baseline (1243.368 us; speedup 1.0000x reference)
//
#include <hip/hip_runtime.h>

#define TT 512
#define BB 2048
#define HH 256
#define KC 32

typedef _Float16 f16x8 __attribute__((ext_vector_type(8)));
typedef _Float16 f16x4 __attribute__((ext_vector_type(4)));
typedef float f32x4 __attribute__((ext_vector_type(4)));

__device__ __forceinline__ float sigf(float z) { return 1.0f / (1.0f + __expf(-z)); }
// order-preserving float<->uint for atomic min/max
__device__ __forceinline__ unsigned f2o(float f) {
    unsigned u = __float_as_uint(f);
    return (u & 0x80000000u) ? ~u : (u | 0x80000000u);
}
__device__ __forceinline__ float o2f(unsigned o) {
    unsigned u = (o & 0x80000000u) ? (o & 0x7fffffffu) : ~o;
    return __uint_as_float(u);
}

// K0: per-t col min/max of X -> analytic out1 normalizer; init colG atomics + scan state.
__global__ __launch_bounds__(256) void k0_stats(const float* __restrict__ X,
                                                const float* __restrict__ W1,
                                                const float* __restrict__ b1,
                                                float* __restrict__ mn1f, float* __restrict__ s1f,
                                                unsigned* __restrict__ colGmn,
                                                unsigned* __restrict__ colGmx,
                                                float2* __restrict__ statep) {
    int t = blockIdx.x, tid = threadIdx.x;
    statep[blockIdx.x * 256 + tid] = make_float2(0.f, 0.f);  // ws never re-poisoned: re-init each launch
    colGmn[(size_t)t * 256 + tid] = 0xFFFFFFFFu;
    colGmx[(size_t)t * 256 + tid] = 0u;
    __shared__ float rmn[256], rmx[256];
    float mn = 3.4e38f, mx = -3.4e38f;
    for (int b = tid; b < BB; b += 256) {
        float v = X[(size_t)b * TT + t];
        mn = fminf(mn, v); mx = fmaxf(mx, v);
    }
    rmn[tid] = mn; rmx[tid] = mx; __syncthreads();
    for (int s = 128; s > 0; s >>= 1) {
        if (tid < s) { rmn[tid] = fminf(rmn[tid], rmn[tid + s]); rmx[tid] = fmaxf(rmx[tid], rmx[tid + s]); }
        __syncthreads();
    }
    float xmn = rmn[0], xmx = rmx[0];
    __syncthreads();
    float w = W1[tid], bb = b1[tid];
    float v0 = w * xmn + bb, v1 = w * xmx + bb;
    rmn[tid] = fminf(v0, v1); rmx[tid] = fmaxf(v0, v1); __syncthreads();
    for (int s = 128; s > 0; s >>= 1) {
        if (tid < s) { rmn[tid] = fminf(rmn[tid], rmn[tid + s]); rmx[tid] = fmaxf(rmx[tid], rmx[tid + s]); }
        __syncthreads();
    }
    if (tid == 0) {
        mn1f[t] = rmn[0];
        s1f[t] = 20.0f / (rmx[0] - rmn[0]);
    }
}

// K0b: W2 f32 -> f16 hi/lo planes (split-precision GEMM operands)
__global__ __launch_bounds__(256) void k0b_cvt(const float* __restrict__ W2,
                                               _Float16* __restrict__ W2hi,
                                               _Float16* __restrict__ W2lo) {
    int i4 = (blockIdx.x * 256 + threadIdx.x) * 4;
    float4 v = *(const float4*)&W2[i4];
    f16x4 h, l;
    h[0] = (_Float16)v.x; h[1] = (_Float16)v.y; h[2] = (_Float16)v.z; h[3] = (_Float16)v.w;
    l[0] = (_Float16)(v.x - (float)h[0]);
    l[1] = (_Float16)(v.y - (float)h[1]);
    l[2] = (_Float16)(v.z - (float)h[2]);
    l[3] = (_Float16)(v.w - (float)h[3]);
    *(f16x4*)&W2hi[i4] = h;
    *(f16x4*)&W2lo[i4] = l;
}

// K1: split-f16 MFMA GEMM (al*bh + ah*bl + ah*bh ~ fp32-exact), tile 128 rows x 256 cols
// (full N: out1 sigmoids computed exactly once). 512 thr = 8 waves (2 row x 4 col),
// wave tile 64x64, KC=32. Epilogue: per-col min/max + 4 LDS-staged coalesced store rounds.
__global__ __launch_bounds__(512) void k1_gemm(const float* __restrict__ X,
                                               const float* __restrict__ W1,
                                               const float* __restrict__ b1,
                                               const _Float16* __restrict__ W2hi,
                                               const _Float16* __restrict__ W2lo,
                                               const float* __restrict__ b2,
                                               const float* __restrict__ mn1f,
                                               const float* __restrict__ s1f,
                                               float* __restrict__ buf,
                                               unsigned* __restrict__ colGmn,
                                               unsigned* __restrict__ colGmx,
                                               int tbase) {
    int tl = blockIdx.z, t = tbase + tl;
    int bBase = blockIdx.x * 128;
    int tid = threadIdx.x;
    __shared__ __align__(16) char smem[64000];
    _Float16* Ah = (_Float16*)smem;                 // [128][40]
    _Float16* Al = (_Float16*)(smem + 10240);       // [128][40]
    _Float16* Bh = (_Float16*)(smem + 20480);       // [256][40]
    _Float16* Bl = (_Float16*)(smem + 40960);       // [256][40] -> ends 61440
    float* C_lds = (float*)smem;                    // [128][68] overlay after compute (34816 B)
    float* x_s = (float*)(smem + 61440);            // 128 f32
    unsigned* cmnL = (unsigned*)(smem + 61952);     // 256
    unsigned* cmxL = (unsigned*)(smem + 62976);     // 256
    if (tid < 128) x_s[tid] = X[(size_t)(bBase + tid) * TT + t];
    if (tid < 256) { cmnL[tid] = 0xFFFFFFFFu; cmxL[tid] = 0u; }
    float mn1 = mn1f[t], s1 = s1f[t];
    int lane = tid & 63, w = tid >> 6;
    int wr = w >> 2, wc = w & 3;                    // wave tile: 64 rows x 64 cols
    int l15 = lane & 15, hi2 = lane >> 4, lk = hi2 * 8;
    f32x4 acc[4][4];
#pragma unroll
    for (int i = 0; i < 4; ++i)
#pragma unroll
        for (int j = 0; j < 4; ++j) acc[i][j] = (f32x4)0.0f;

    int sr = tid >> 2, skg = (tid & 3) * 8;         // A staging: row 0..127, k {0,8,16,24}
    for (int kc = 0; kc < HH; kc += KC) {
        __syncthreads();  // protects x_s (iter 0) and LDS reuse (iter>0)
        {   // stage A = out1 hi/lo (8 sigmoids + split per thread)
            float x = x_s[sr];
            float4 wa = *(const float4*)&W1[kc + skg];
            float4 wb = *(const float4*)&W1[kc + skg + 4];
            float4 ba = *(const float4*)&b1[kc + skg];
            float4 bb = *(const float4*)&b1[kc + skg + 4];
            float a0 = sigf((x * wa.x + ba.x - mn1) * s1);
            float a1 = sigf((x * wa.y + ba.y - mn1) * s1);
            float a2 = sigf((x * wa.z + ba.z - mn1) * s1);
            float a3 = sigf((x * wa.w + ba.w - mn1) * s1);
            float a4 = sigf((x * wb.x + bb.x - mn1) * s1);
            float a5 = sigf((x * wb.y + bb.y - mn1) * s1);
            float a6 = sigf((x * wb.z + bb.z - mn1) * s1);
            float a7 = sigf((x * wb.w + bb.w - mn1) * s1);
            f16x8 hv, lv;
            hv[0] = (_Float16)a0; lv[0] = (_Float16)(a0 - (float)hv[0]);
            hv[1] = (_Float16)a1; lv[1] = (_Float16)(a1 - (float)hv[1]);
            hv[2] = (_Float16)a2; lv[2] = (_Float16)(a2 - (float)hv[2]);
            hv[3] = (_Float16)a3; lv[3] = (_Float16)(a3 - (float)hv[3]);
            hv[4] = (_Float16)a4; lv[4] = (_Float16)(a4 - (float)hv[4]);
            hv[5] = (_Float16)a5; lv[5] = (_Float16)(a5 - (float)hv[5]);
            hv[6] = (_Float16)a6; lv[6] = (_Float16)(a6 - (float)hv[6]);
            hv[7] = (_Float16)a7; lv[7] = (_Float16)(a7 - (float)hv[7]);
            *(f16x8*)&Ah[sr * 40 + skg] = hv;
            *(f16x8*)&Al[sr * 40 + skg] = lv;
        }
        // stage B = W2 hi/lo, 256 cols x 32 k (2 cols per thread per plane)
#pragma unroll
        for (int it = 0; it < 2; ++it) {
            int idx = it * 512 + tid;
            int c = idx >> 2, kg = (idx & 3) * 8;
            size_t gsrc = (size_t)c * HH + kc + kg;
            *(f16x8*)&Bh[c * 40 + kg] = *(const f16x8*)&W2hi[gsrc];
            *(f16x8*)&Bl[c * 40 + kg] = *(const f16x8*)&W2lo[gsrc];
        }
        __syncthreads();
        f16x8 ah[4], alo[4], bh4[4], bl4[4];
#pragma unroll
        for (int i = 0; i < 4; ++i) {
            int ro = (wr * 64 + i * 16 + l15) * 40 + lk;
            ah[i] = *(const f16x8*)&Ah[ro];
            alo[i] = *(const f16x8*)&Al[ro];
        }
#pragma unroll
        for (int j = 0; j < 4; ++j) {
            int co = (wc * 64 + j * 16 + l15) * 40 + lk;
            bh4[j] = *(const f16x8*)&Bh[co];
            bl4[j] = *(const f16x8*)&Bl[co];
        }
#pragma unroll
        for (int i = 0; i < 4; ++i)
#pragma unroll
            for (int j = 0; j < 4; ++j) {
                acc[i][j] = __builtin_amdgcn_mfma_f32_16x16x32_f16(alo[i], bh4[j], acc[i][j], 0, 0, 0);
                acc[i][j] = __builtin_amdgcn_mfma_f32_16x16x32_f16(ah[i], bl4[j], acc[i][j], 0, 0, 0);
                acc[i][j] = __builtin_amdgcn_mfma_f32_16x16x32_f16(ah[i], bh4[j], acc[i][j], 0, 0, 0);
            }
    }
    // epilogue: +b2, per-col min/max into LDS atomics
    float b2r[4];
#pragma unroll
    for (int j = 0; j < 4; ++j) b2r[j] = b2[wc * 64 + j * 16 + l15];
#pragma unroll
    for (int j = 0; j < 4; ++j) {
        int cl = wc * 64 + j * 16 + l15;
        float vmn = 3.4e38f, vmx = -3.4e38f;
#pragma unroll
        for (int i = 0; i < 4; ++i)
#pragma unroll
            for (int q = 0; q < 4; ++q) {
                float v = acc[i][j][q] + b2r[j];
                vmn = fminf(vmn, v); vmx = fmaxf(vmx, v);
            }
        vmn = fminf(vmn, __shfl_xor(vmn, 16)); vmn = fminf(vmn, __shfl_xor(vmn, 32));
        vmx = fmaxf(vmx, __shfl_xor(vmx, 16)); vmx = fmaxf(vmx, __shfl_xor(vmx, 32));
        if (hi2 == 0) {
            atomicMin(&cmnL[cl], f2o(vmn));
            atomicMax(&cmxL[cl], f2o(vmx));
        }
    }
    __syncthreads();  // A/B LDS dead; safe to overlay C_lds
    // 4 column rounds of 64: waves with wc==r stage, all threads copy out coalesced
#pragma unroll
    for (int r = 0; r < 4; ++r) {
        if (wc == r) {
#pragma unroll
            for (int i = 0; i < 4; ++i)
#pragma unroll
                for (int j = 0; j < 4; ++j)
#pragma unroll
                    for (int q = 0; q < 4; ++q)
                        C_lds[(wr * 64 + i * 16 + hi2 * 4 + q) * 68 + j * 16 + l15] =
                            acc[i][j][q] + b2r[j];
        }
        __syncthreads();
#pragma unroll
        for (int it = 0; it < 4; ++it) {
            int idx = it * 512 + tid;
            int row = idx >> 4, c4 = idx & 15;
            float4 v = *(const float4*)&C_lds[row * 68 + c4 * 4];
            *(float4*)&buf[((size_t)tl * BB + bBase + row) * HH + r * 64 + c4 * 4] = v;
        }
        __syncthreads();
    }
    if (tid < 256) {
        atomicMin(&colGmn[(size_t)t * 256 + tid], cmnL[tid]);
        atomicMax(&colGmx[(size_t)t * 256 + tid], cmxL[tid]);
    }
}

// K1b: per-t analytic normalizers for out2 and (via sigmoid monotonicity) jpre/kpre.
__global__ __launch_bounds__(256) void k1b(const unsigned* __restrict__ colGmn,
                                           const unsigned* __restrict__ colGmx,
                                           const float* __restrict__ j_w,
                                           const float* __restrict__ k_w,
                                           float* __restrict__ mn2f, float* __restrict__ s2f,
                                           float* __restrict__ mjf, float* __restrict__ sjf,
                                           float* __restrict__ mkf, float* __restrict__ skf,
                                           int tbase) {
    int t = tbase + blockIdx.x, tid = threadIdx.x;
    __shared__ float ra[256], rb[256];
    float cmn = o2f(colGmn[(size_t)t * 256 + tid]);
    float cmx = o2f(colGmx[(size_t)t * 256 + tid]);
    ra[tid] = cmn; rb[tid] = cmx; __syncthreads();
    for (int s = 128; s > 0; s >>= 1) {
        if (tid < s) { ra[tid] = fminf(ra[tid], ra[tid + s]); rb[tid] = fmaxf(rb[tid], rb[tid + s]); }
        __syncthreads();
    }
    float mn2 = ra[0], mx2 = rb[0];
    float s2 = 20.0f / (mx2 - mn2);
    __syncthreads();
    // endpoint transform (exactly the scan's expression); j half = cols 0..127, k half = 128..255
    float wv = (tid < 128) ? j_w[tid] : k_w[tid - 128];
    float ea = sigf((cmn - mn2) * s2) * wv;
    float eb = sigf((cmx - mn2) * s2) * wv;
    ra[tid] = fminf(ea, eb); rb[tid] = fmaxf(ea, eb); __syncthreads();
    for (int s = 64; s > 0; s >>= 1) {
        if ((tid & 127) < s) { ra[tid] = fminf(ra[tid], ra[tid + s]); rb[tid] = fmaxf(rb[tid], rb[tid + s]); }
        __syncthreads();
    }
    if (tid == 0) {
        mn2f[t] = mn2; s2f[t] = s2;
        mjf[t] = ra[0]; sjf[t] = 20.0f / (rb[0] - ra[0]);
    }
    if (tid == 128) {
        mkf[t] = ra[128]; skf[t] = 20.0f / (rb[128] - ra[128]);
    }
}

// K3: affine scan; computes jpre/kpre + gates on the fly from out2_pre.
__global__ __launch_bounds__(256) void k3_scan(const float* __restrict__ buf,
                                               const float* __restrict__ W4,
                                               const float* __restrict__ b4,
                                               const float* __restrict__ mn2f, const float* __restrict__ s2f,
                                               const float* __restrict__ mjf, const float* __restrict__ sjf,
                                               const float* __restrict__ mkf, const float* __restrict__ skf,
                                               const float* __restrict__ j_w, const float* __restrict__ k_w,
                                               float2* __restrict__ statep,
                                               float* __restrict__ out4p,
                                               int tbase, int TC) {
    __shared__ float n2L[512], c2L[512], mjL[512], sjL[512], mkL[512], skL[512];
    int tid = threadIdx.x;
    for (int tl = tid; tl < TC; tl += 256) {
        int t = tbase + tl;
        n2L[tl] = mn2f[t]; c2L[tl] = s2f[t];
        mjL[tl] = mjf[t]; sjL[tl] = sjf[t];
        mkL[tl] = mkf[t]; skL[tl] = skf[t];
    }
    __syncthreads();
    int wave = tid >> 6, lane = tid & 63;
    int b = blockIdx.x * 4 + wave;
    float w40 = W4[2 * lane], w41 = W4[2 * lane + 1];
    float jw0 = j_w[2 * lane], jw1 = j_w[2 * lane + 1];
    float kw0 = k_w[2 * lane], kw1 = k_w[2 * lane + 1];
    float bb4 = b4[0];
    float2 stv = statep[b * 64 + lane];
    float s0 = stv.x, s1v = stv.y;
    const float2* basep = (const float2*)buf;
    const int rowstride = BB * 128;
    int off0 = b * 128 + lane;
    float rsave = 0.f;
    float2 jq[8], kq[8];
#pragma unroll
    for (int u = 0; u < 8; ++u) {
        jq[u] = basep[(size_t)u * rowstride + off0];
        kq[u] = basep[(size_t)u * rowstride + off0 + 64];
    }
    for (int t0 = 0; t0 < TC; t0 += 8) {
#pragma unroll
        for (int u = 0; u < 8; ++u) {
            int tl = t0 + u;
            float2 jp = jq[u], kp = kq[u];
            int tn = tl + 8;
            if (tn < TC) {
                jq[u] = basep[(size_t)tn * rowstride + off0];
                kq[u] = basep[(size_t)tn * rowstride + off0 + 64];
            }
            float n2 = n2L[tl], c2 = c2L[tl];
            float pj0 = sigf((jp.x - n2) * c2) * jw0;
            float pj1 = sigf((jp.y - n2) * c2) * jw1;
            float pk0 = sigf((kp.x - n2) * c2) * kw0;
            float pk1 = sigf((kp.y - n2) * c2) * kw1;
            float ij0 = sigf((pj0 - mjL[tl]) * sjL[tl]);
            float ij1 = sigf((pj1 - mjL[tl]) * sjL[tl]);
            float ik0 = sigf((pk0 - mkL[tl]) * skL[tl]);
            float ik1 = sigf((pk1 - mkL[tl]) * skL[tl]);
            s0 = ij0 + s0 * (1.0f - ij0 - ik0);
            s1v = ij1 + s1v * (1.0f - ij1 - ik1);
            float r = s0 * w40 + s1v * w41;
#pragma unroll
            for (int m = 1; m < 64; m <<= 1) r += __shfl_xor(r, m);
            if (lane == (tl & 63)) rsave = r + bb4;
        }
        if (((t0 + 8) & 63) == 0) {  // coalesced 64-step flush
            int base = t0 + 8 - 64;
            out4p[(size_t)b * TT + tbase + base + lane] = rsave;
        }
    }
    if (TC < 64 && lane < TC) out4p[(size_t)b * TT + tbase + lane] = rsave;
    statep[b * 64 + lane] = make_float2(s0, s1v);
}

__global__ __launch_bounds__(256) void k3b(const float* __restrict__ out4p,
                                           float* __restrict__ mn4f, float* __restrict__ s4f) {
    int t = blockIdx.x, tid = threadIdx.x;
    __shared__ float rmn[256], rmx[256];
    float mn = 3.4e38f, mx = -3.4e38f;
    for (int b = tid; b < BB; b += 256) {
        float v = out4p[(size_t)b * TT + t];
        mn = fminf(mn, v); mx = fmaxf(mx, v);
    }
    rmn[tid] = mn; rmx[tid] = mx; __syncthreads();
    for (int s = 128; s > 0; s >>= 1) {
        if (tid < s) { rmn[tid] = fminf(rmn[tid], rmn[tid + s]); rmx[tid] = fmaxf(rmx[tid], rmx[tid + s]); }
        __syncthreads();
    }
    if (tid == 0) { mn4f[t] = rmn[0]; s4f[t] = 20.0f / (rmx[0] - rmn[0]); }
}

__global__ __launch_bounds__(256) void k4_final(float* __restrict__ out,
                                                const float* __restrict__ mn4f,
                                                const float* __restrict__ s4f) {
    int i = blockIdx.x * 256 + threadIdx.x;
    float4 v = ((const float4*)out)[i];
    int t0 = (i * 4) & (TT - 1);
    float4 mn = *(const float4*)&mn4f[t0];
    float4 sc = *(const float4*)&s4f[t0];
    float4 r;
    r.x = sigf((v.x - mn.x) * sc.x);
    r.y = sigf((v.y - mn.y) * sc.y);
    r.z = sigf((v.z - mn.z) * sc.z);
    r.w = sigf((v.w - mn.w) * sc.w);
    ((float4*)out)[i] = r;
}

extern "C" void kernel_launch(void* const* d_in, const int* in_sizes, int n_in,
                              void* d_out, int out_size, void* d_ws, size_t ws_size,
                              hipStream_t stream) {
    const float* X  = (const float*)d_in[0];
    const float* W1 = (const float*)d_in[1];
    const float* b1 = (const float*)d_in[2];
    const float* W2 = (const float*)d_in[3];
    const float* b2 = (const float*)d_in[4];
    const float* W4 = (const float*)d_in[5];
    const float* b4 = (const float*)d_in[6];
    const float* j_w = (const float*)d_in[7];
    const float* k_w = (const float*)d_in[8];
    float* out = (float*)d_out;

    const size_t stateB = (size_t)BB * 64 * sizeof(float2);  // 1 MB
    const size_t colGB  = (size_t)TT * 256 * 2 * 4;          // 1 MB
    const size_t w2hB   = (size_t)HH * HH * 2 * 2;           // 256 KB (hi+lo)
    const size_t statsB = 65536;
    int TC = 512;
    while (TC > 8 && ((size_t)TC * BB * HH * 4 + stateB + colGB + w2hB + statsB) > ws_size) TC >>= 1;
    int NC = TT / TC;

    char* w = (char*)d_ws;
    float* buf = (float*)w;
    size_t off = (size_t)TC * BB * HH * 4;
    float2* statep = (float2*)(w + off); off += stateB;
    unsigned* colGmn = (unsigned*)(w + off); off += colGB / 2;
    unsigned* colGmx = (unsigned*)(w + off); off += colGB / 2;
    _Float16* W2hi = (_Float16*)(w + off); off += w2hB / 2;
    _Float16* W2lo = (_Float16*)(w + off); off += w2hB / 2;
    float* fst = (float*)(w + off);
    float* mn1f = fst;        float* s1f = fst + 512;
    float* mn2f = fst + 1024; float* s2f = fst + 1536;
    float* mjf  = fst + 2048; float* sjf = fst + 2560;
    float* mkf  = fst + 3072; float* skf = fst + 3584;
    float* mn4f = fst + 4096; float* s4f = fst + 4608;
    float* out4p = out;  // (B,T) pre-activation lives in d_out, normalized in place

    k0_stats<<<512, 256, 0, stream>>>(X, W1, b1, mn1f, s1f, colGmn, colGmx, statep);
    k0b_cvt<<<64, 256, 0, stream>>>(W2, W2hi, W2lo);
    for (int c = 0; c < NC; ++c) {
        int tbase = c * TC;
        k1_gemm<<<dim3(BB / 128, 1, TC), 512, 0, stream>>>(X, W1, b1, W2hi, W2lo, b2, mn1f, s1f,
                                                           buf, colGmn, colGmx, tbase);
        k1b<<<TC, 256, 0, stream>>>(colGmn, colGmx, j_w, k_w, mn2f, s2f, mjf, sjf, mkf, skf, tbase);
        k3_scan<<<512, 256, 0, stream>>>(buf, W4, b4, mn2f, s2f, mjf, sjf, mkf, skf,
                                         j_w, k_w, statep, out4p, tbase, TC);
    }
    k3b<<<512, 256, 0, stream>>>(out4p, mn4f, s4f);
    k4_final<<<1024, 256, 0, stream>>>(out, mn4f, s4f);
}

// Round 6
// 1221.853 us; speedup vs baseline: 1.0176x; 1.0176x over previous
//
#include <hip/hip_runtime.h>

#define TT 512
#define BB 2048
#define HH 256
#define KC 32

typedef _Float16 f16x8 __attribute__((ext_vector_type(8)));
typedef _Float16 f16x4 __attribute__((ext_vector_type(4)));
typedef float f32x4 __attribute__((ext_vector_type(4)));

__device__ __forceinline__ float sigf(float z) { return 1.0f / (1.0f + __expf(-z)); }
// order-preserving float<->uint for atomic min/max
__device__ __forceinline__ unsigned f2o(float f) {
    unsigned u = __float_as_uint(f);
    return (u & 0x80000000u) ? ~u : (u | 0x80000000u);
}
__device__ __forceinline__ float o2f(unsigned o) {
    unsigned u = (o & 0x80000000u) ? (o & 0x7fffffffu) : ~o;
    return __uint_as_float(u);
}

// K0: per-t col min/max of X -> analytic out1 normalizer; init colG atomics + scan state.
__global__ __launch_bounds__(256) void k0_stats(const float* __restrict__ X,
                                                const float* __restrict__ W1,
                                                const float* __restrict__ b1,
                                                float* __restrict__ mn1f, float* __restrict__ s1f,
                                                unsigned* __restrict__ colGmn,
                                                unsigned* __restrict__ colGmx,
                                                float2* __restrict__ statep) {
    int t = blockIdx.x, tid = threadIdx.x;
    statep[blockIdx.x * 256 + tid] = make_float2(0.f, 0.f);  // ws never re-poisoned: re-init each launch
    colGmn[(size_t)t * 256 + tid] = 0xFFFFFFFFu;
    colGmx[(size_t)t * 256 + tid] = 0u;
    __shared__ float rmn[256], rmx[256];
    float mn = 3.4e38f, mx = -3.4e38f;
    for (int b = tid; b < BB; b += 256) {
        float v = X[(size_t)b * TT + t];
        mn = fminf(mn, v); mx = fmaxf(mx, v);
    }
    rmn[tid] = mn; rmx[tid] = mx; __syncthreads();
    for (int s = 128; s > 0; s >>= 1) {
        if (tid < s) { rmn[tid] = fminf(rmn[tid], rmn[tid + s]); rmx[tid] = fmaxf(rmx[tid], rmx[tid + s]); }
        __syncthreads();
    }
    float xmn = rmn[0], xmx = rmx[0];
    __syncthreads();
    float w = W1[tid], bb = b1[tid];
    float v0 = w * xmn + bb, v1 = w * xmx + bb;
    rmn[tid] = fminf(v0, v1); rmx[tid] = fmaxf(v0, v1); __syncthreads();
    for (int s = 128; s > 0; s >>= 1) {
        if (tid < s) { rmn[tid] = fminf(rmn[tid], rmn[tid + s]); rmx[tid] = fmaxf(rmx[tid], rmx[tid + s]); }
        __syncthreads();
    }
    if (tid == 0) {
        mn1f[t] = rmn[0];
        s1f[t] = 20.0f / (rmx[0] - rmn[0]);
    }
}

// K0b: W2 f32 -> f16 hi/lo planes (split-precision GEMM operands)
__global__ __launch_bounds__(256) void k0b_cvt(const float* __restrict__ W2,
                                               _Float16* __restrict__ W2hi,
                                               _Float16* __restrict__ W2lo) {
    int i4 = (blockIdx.x * 256 + threadIdx.x) * 4;
    float4 v = *(const float4*)&W2[i4];
    f16x4 h, l;
    h[0] = (_Float16)v.x; h[1] = (_Float16)v.y; h[2] = (_Float16)v.z; h[3] = (_Float16)v.w;
    l[0] = (_Float16)(v.x - (float)h[0]);
    l[1] = (_Float16)(v.y - (float)h[1]);
    l[2] = (_Float16)(v.z - (float)h[2]);
    l[3] = (_Float16)(v.w - (float)h[3]);
    *(f16x4*)&W2hi[i4] = h;
    *(f16x4*)&W2lo[i4] = l;
}

// K1: split-f16 MFMA GEMM (al*bh + ah*bl + ah*bh ~ fp32-exact), tile 64 rows x 256 cols.
// 256 thr = 4 waves, each wave owns a 64-col slice (wave tile 64x64, acc 4x4).
// B-fragments load DIRECTLY from global (L2-hot, never staged in LDS).
// A (out1 hi/lo) double-buffered in LDS -> ONE barrier per K-chunk.
// Epilogue: per-wave LDS scratch transpose -> aligned float4 stores, no block barriers.
__global__ __launch_bounds__(256) void k1_gemm(const float* __restrict__ X,
                                               const float* __restrict__ W1,
                                               const float* __restrict__ b1,
                                               const _Float16* __restrict__ W2hi,
                                               const _Float16* __restrict__ W2lo,
                                               const float* __restrict__ b2,
                                               const float* __restrict__ mn1f,
                                               const float* __restrict__ s1f,
                                               float* __restrict__ buf,
                                               unsigned* __restrict__ colGmn,
                                               unsigned* __restrict__ colGmx,
                                               int tbase) {
    int tl = blockIdx.z, t = tbase + tl;
    int bBase = blockIdx.x * 64;
    int tid = threadIdx.x;
    __shared__ __align__(16) char smem[39936];
    _Float16* AB = (_Float16*)smem;              // [2 buf][2 plane][64 rows][40 k-halves]
    // halves offsets: buf*5120 + plane*2560 + row*40 + k
    float* scratch = (float*)(smem + 20480);     // per-wave [16][68] f32 (4 waves x 4352 B)
    unsigned* cmnL = (unsigned*)(smem + 37888);  // 256
    unsigned* cmxL = (unsigned*)(smem + 38912);  // 256
    cmnL[tid] = 0xFFFFFFFFu; cmxL[tid] = 0u;
    float mn1 = mn1f[t], s1 = s1f[t];
    int lane = tid & 63, w = tid >> 6;           // w = wave = col-slice
    int l15 = lane & 15, hi2 = lane >> 4, lk = hi2 * 8;
    int sr = tid >> 2, skg = (tid & 3) * 8;      // A staging: row 0..63, k {0,8,16,24}
    float xr = X[(size_t)(bBase + sr) * TT + t];

    const _Float16* pbh[4];
    const _Float16* pbl[4];
#pragma unroll
    for (int j = 0; j < 4; ++j) {
        size_t co = (size_t)(w * 64 + j * 16 + l15) * HH + lk;
        pbh[j] = W2hi + co; pbl[j] = W2lo + co;
    }

    f32x4 acc[4][4];
#pragma unroll
    for (int i = 0; i < 4; ++i)
#pragma unroll
        for (int j = 0; j < 4; ++j) acc[i][j] = (f32x4)0.0f;

    // stage A chunk kc into LDS buffer bsel (hi+lo planes), 8 values/thread
#define STAGE_A(bsel, kc)                                                        \
    {                                                                            \
        float4 wa = *(const float4*)&W1[(kc) + skg];                             \
        float4 wb = *(const float4*)&W1[(kc) + skg + 4];                         \
        float4 ba = *(const float4*)&b1[(kc) + skg];                             \
        float4 bb = *(const float4*)&b1[(kc) + skg + 4];                         \
        float a0 = sigf((xr * wa.x + ba.x - mn1) * s1);                          \
        float a1 = sigf((xr * wa.y + ba.y - mn1) * s1);                          \
        float a2 = sigf((xr * wa.z + ba.z - mn1) * s1);                          \
        float a3 = sigf((xr * wa.w + ba.w - mn1) * s1);                          \
        float a4 = sigf((xr * wb.x + bb.x - mn1) * s1);                          \
        float a5 = sigf((xr * wb.y + bb.y - mn1) * s1);                          \
        float a6 = sigf((xr * wb.z + bb.z - mn1) * s1);                          \
        float a7 = sigf((xr * wb.w + bb.w - mn1) * s1);                          \
        f16x8 hv, lv;                                                            \
        hv[0] = (_Float16)a0; lv[0] = (_Float16)(a0 - (float)hv[0]);             \
        hv[1] = (_Float16)a1; lv[1] = (_Float16)(a1 - (float)hv[1]);             \
        hv[2] = (_Float16)a2; lv[2] = (_Float16)(a2 - (float)hv[2]);             \
        hv[3] = (_Float16)a3; lv[3] = (_Float16)(a3 - (float)hv[3]);             \
        hv[4] = (_Float16)a4; lv[4] = (_Float16)(a4 - (float)hv[4]);             \
        hv[5] = (_Float16)a5; lv[5] = (_Float16)(a5 - (float)hv[5]);             \
        hv[6] = (_Float16)a6; lv[6] = (_Float16)(a6 - (float)hv[6]);             \
        hv[7] = (_Float16)a7; lv[7] = (_Float16)(a7 - (float)hv[7]);             \
        _Float16* ap = AB + (bsel) * 5120 + sr * 40 + skg;                       \
        *(f16x8*)ap = hv;                                                        \
        *(f16x8*)(ap + 2560) = lv;                                               \
    }

    STAGE_A(0, 0);
    __syncthreads();
#pragma unroll
    for (int c = 0; c < 8; ++c) {
        int cur = c & 1;
        if (c < 7) STAGE_A(cur ^ 1, (c + 1) * KC);
        int kc = c * KC;
        f16x8 bh4[4], bl4[4];
#pragma unroll
        for (int j = 0; j < 4; ++j) {
            bh4[j] = *(const f16x8*)(pbh[j] + kc);
            bl4[j] = *(const f16x8*)(pbl[j] + kc);
        }
        f16x8 ah[4], alo[4];
        const _Float16* abase = AB + cur * 5120;
#pragma unroll
        for (int i = 0; i < 4; ++i) {
            int ro = (i * 16 + l15) * 40 + lk;
            ah[i] = *(const f16x8*)(abase + ro);
            alo[i] = *(const f16x8*)(abase + 2560 + ro);
        }
#pragma unroll
        for (int i = 0; i < 4; ++i)
#pragma unroll
            for (int j = 0; j < 4; ++j) {
                acc[i][j] = __builtin_amdgcn_mfma_f32_16x16x32_f16(alo[i], bh4[j], acc[i][j], 0, 0, 0);
                acc[i][j] = __builtin_amdgcn_mfma_f32_16x16x32_f16(ah[i], bl4[j], acc[i][j], 0, 0, 0);
                acc[i][j] = __builtin_amdgcn_mfma_f32_16x16x32_f16(ah[i], bh4[j], acc[i][j], 0, 0, 0);
            }
        __syncthreads();
    }
#undef STAGE_A

    // +b2 folded into acc, then per-col min/max (shfl over hi2 -> LDS atomics)
    float b2r[4];
#pragma unroll
    for (int j = 0; j < 4; ++j) b2r[j] = b2[w * 64 + j * 16 + l15];
#pragma unroll
    for (int j = 0; j < 4; ++j) {
        float vmn = 3.4e38f, vmx = -3.4e38f;
#pragma unroll
        for (int i = 0; i < 4; ++i)
#pragma unroll
            for (int q = 0; q < 4; ++q) {
                float v = acc[i][j][q] + b2r[j];
                acc[i][j][q] = v;
                vmn = fminf(vmn, v); vmx = fmaxf(vmx, v);
            }
        vmn = fminf(vmn, __shfl_xor(vmn, 16)); vmn = fminf(vmn, __shfl_xor(vmn, 32));
        vmx = fmaxf(vmx, __shfl_xor(vmx, 16)); vmx = fmaxf(vmx, __shfl_xor(vmx, 32));
        if (hi2 == 0) {
            int cl = w * 64 + j * 16 + l15;
            atomicMin(&cmnL[cl], f2o(vmn));
            atomicMax(&cmxL[cl], f2o(vmx));
        }
    }
    // per-wave transpose via scratch (DS ops in-order per wave; no block barrier),
    // then aligned 64-B float4 segments to global
    float* myscr = scratch + w * 1088;  // [16][68]
#pragma unroll
    for (int i = 0; i < 4; ++i) {
#pragma unroll
        for (int j = 0; j < 4; ++j)
#pragma unroll
            for (int q = 0; q < 4; ++q)
                myscr[(hi2 * 4 + q) * 68 + j * 16 + l15] = acc[i][j][q];
        __builtin_amdgcn_s_waitcnt(0xC07F);  // lgkmcnt(0): scratch writes visible wave-wide
        float* dst = buf + ((size_t)tl * BB + bBase + i * 16 + l15) * HH + w * 64;
#pragma unroll
        for (int rr = 0; rr < 4; ++rr) {
            float4 v = *(const float4*)&myscr[l15 * 68 + rr * 16 + hi2 * 4];
            *(float4*)&dst[rr * 16 + hi2 * 4] = v;
        }
        __builtin_amdgcn_s_waitcnt(0xC07F);  // drain reads before next i overwrites scratch
    }
    __syncthreads();
    atomicMin(&colGmn[(size_t)t * 256 + tid], cmnL[tid]);
    atomicMax(&colGmx[(size_t)t * 256 + tid], cmxL[tid]);
}

// K1b: per-t analytic normalizers for out2 and (via sigmoid monotonicity) jpre/kpre.
__global__ __launch_bounds__(256) void k1b(const unsigned* __restrict__ colGmn,
                                           const unsigned* __restrict__ colGmx,
                                           const float* __restrict__ j_w,
                                           const float* __restrict__ k_w,
                                           float* __restrict__ mn2f, float* __restrict__ s2f,
                                           float* __restrict__ mjf, float* __restrict__ sjf,
                                           float* __restrict__ mkf, float* __restrict__ skf,
                                           int tbase) {
    int t = tbase + blockIdx.x, tid = threadIdx.x;
    __shared__ float ra[256], rb[256];
    float cmn = o2f(colGmn[(size_t)t * 256 + tid]);
    float cmx = o2f(colGmx[(size_t)t * 256 + tid]);
    ra[tid] = cmn; rb[tid] = cmx; __syncthreads();
    for (int s = 128; s > 0; s >>= 1) {
        if (tid < s) { ra[tid] = fminf(ra[tid], ra[tid + s]); rb[tid] = fmaxf(rb[tid], rb[tid + s]); }
        __syncthreads();
    }
    float mn2 = ra[0], mx2 = rb[0];
    float s2 = 20.0f / (mx2 - mn2);
    __syncthreads();
    // endpoint transform (exactly the scan's expression); j half = cols 0..127, k half = 128..255
    float wv = (tid < 128) ? j_w[tid] : k_w[tid - 128];
    float ea = sigf((cmn - mn2) * s2) * wv;
    float eb = sigf((cmx - mn2) * s2) * wv;
    ra[tid] = fminf(ea, eb); rb[tid] = fmaxf(ea, eb); __syncthreads();
    for (int s = 64; s > 0; s >>= 1) {
        if ((tid & 127) < s) { ra[tid] = fminf(ra[tid], ra[tid + s]); rb[tid] = fmaxf(rb[tid], rb[tid + s]); }
        __syncthreads();
    }
    if (tid == 0) {
        mn2f[t] = mn2; s2f[t] = s2;
        mjf[t] = ra[0]; sjf[t] = 20.0f / (rb[0] - ra[0]);
    }
    if (tid == 128) {
        mkf[t] = ra[128]; skf[t] = 20.0f / (rb[128] - ra[128]);
    }
}

// K3: affine scan; computes jpre/kpre + gates on the fly from out2_pre.
__global__ __launch_bounds__(256) void k3_scan(const float* __restrict__ buf,
                                               const float* __restrict__ W4,
                                               const float* __restrict__ b4,
                                               const float* __restrict__ mn2f, const float* __restrict__ s2f,
                                               const float* __restrict__ mjf, const float* __restrict__ sjf,
                                               const float* __restrict__ mkf, const float* __restrict__ skf,
                                               const float* __restrict__ j_w, const float* __restrict__ k_w,
                                               float2* __restrict__ statep,
                                               float* __restrict__ out4p,
                                               int tbase, int TC) {
    __shared__ float n2L[512], c2L[512], mjL[512], sjL[512], mkL[512], skL[512];
    int tid = threadIdx.x;
    for (int tl = tid; tl < TC; tl += 256) {
        int t = tbase + tl;
        n2L[tl] = mn2f[t]; c2L[tl] = s2f[t];
        mjL[tl] = mjf[t]; sjL[tl] = sjf[t];
        mkL[tl] = mkf[t]; skL[tl] = skf[t];
    }
    __syncthreads();
    int wave = tid >> 6, lane = tid & 63;
    int b = blockIdx.x * 4 + wave;
    float w40 = W4[2 * lane], w41 = W4[2 * lane + 1];
    float jw0 = j_w[2 * lane], jw1 = j_w[2 * lane + 1];
    float kw0 = k_w[2 * lane], kw1 = k_w[2 * lane + 1];
    float bb4 = b4[0];
    float2 stv = statep[b * 64 + lane];
    float s0 = stv.x, s1v = stv.y;
    const float2* basep = (const float2*)buf;
    const int rowstride = BB * 128;
    int off0 = b * 128 + lane;
    float rsave = 0.f;
    float2 jq[8], kq[8];
#pragma unroll
    for (int u = 0; u < 8; ++u) {
        jq[u] = basep[(size_t)u * rowstride + off0];
        kq[u] = basep[(size_t)u * rowstride + off0 + 64];
    }
    for (int t0 = 0; t0 < TC; t0 += 8) {
#pragma unroll
        for (int u = 0; u < 8; ++u) {
            int tl = t0 + u;
            float2 jp = jq[u], kp = kq[u];
            int tn = tl + 8;
            if (tn < TC) {
                jq[u] = basep[(size_t)tn * rowstride + off0];
                kq[u] = basep[(size_t)tn * rowstride + off0 + 64];
            }
            float n2 = n2L[tl], c2 = c2L[tl];
            float pj0 = sigf((jp.x - n2) * c2) * jw0;
            float pj1 = sigf((jp.y - n2) * c2) * jw1;
            float pk0 = sigf((kp.x - n2) * c2) * kw0;
            float pk1 = sigf((kp.y - n2) * c2) * kw1;
            float ij0 = sigf((pj0 - mjL[tl]) * sjL[tl]);
            float ij1 = sigf((pj1 - mjL[tl]) * sjL[tl]);
            float ik0 = sigf((pk0 - mkL[tl]) * skL[tl]);
            float ik1 = sigf((pk1 - mkL[tl]) * skL[tl]);
            s0 = ij0 + s0 * (1.0f - ij0 - ik0);
            s1v = ij1 + s1v * (1.0f - ij1 - ik1);
            float r = s0 * w40 + s1v * w41;
#pragma unroll
            for (int m = 1; m < 64; m <<= 1) r += __shfl_xor(r, m);
            if (lane == (tl & 63)) rsave = r + bb4;
        }
        if (((t0 + 8) & 63) == 0) {  // coalesced 64-step flush
            int base = t0 + 8 - 64;
            out4p[(size_t)b * TT + tbase + base + lane] = rsave;
        }
    }
    if (TC < 64 && lane < TC) out4p[(size_t)b * TT + tbase + lane] = rsave;
    statep[b * 64 + lane] = make_float2(s0, s1v);
}

__global__ __launch_bounds__(256) void k3b(const float* __restrict__ out4p,
                                           float* __restrict__ mn4f, float* __restrict__ s4f) {
    int t = blockIdx.x, tid = threadIdx.x;
    __shared__ float rmn[256], rmx[256];
    float mn = 3.4e38f, mx = -3.4e38f;
    for (int b = tid; b < BB; b += 256) {
        float v = out4p[(size_t)b * TT + t];
        mn = fminf(mn, v); mx = fmaxf(mx, v);
    }
    rmn[tid] = mn; rmx[tid] = mx; __syncthreads();
    for (int s = 128; s > 0; s >>= 1) {
        if (tid < s) { rmn[tid] = fminf(rmn[tid], rmn[tid + s]); rmx[tid] = fmaxf(rmx[tid], rmx[tid + s]); }
        __syncthreads();
    }
    if (tid == 0) { mn4f[t] = rmn[0]; s4f[t] = 20.0f / (rmx[0] - rmn[0]); }
}

__global__ __launch_bounds__(256) void k4_final(float* __restrict__ out,
                                                const float* __restrict__ mn4f,
                                                const float* __restrict__ s4f) {
    int i = blockIdx.x * 256 + threadIdx.x;
    float4 v = ((const float4*)out)[i];
    int t0 = (i * 4) & (TT - 1);
    float4 mn = *(const float4*)&mn4f[t0];
    float4 sc = *(const float4*)&s4f[t0];
    float4 r;
    r.x = sigf((v.x - mn.x) * sc.x);
    r.y = sigf((v.y - mn.y) * sc.y);
    r.z = sigf((v.z - mn.z) * sc.z);
    r.w = sigf((v.w - mn.w) * sc.w);
    ((float4*)out)[i] = r;
}

extern "C" void kernel_launch(void* const* d_in, const int* in_sizes, int n_in,
                              void* d_out, int out_size, void* d_ws, size_t ws_size,
                              hipStream_t stream) {
    const float* X  = (const float*)d_in[0];
    const float* W1 = (const float*)d_in[1];
    const float* b1 = (const float*)d_in[2];
    const float* W2 = (const float*)d_in[3];
    const float* b2 = (const float*)d_in[4];
    const float* W4 = (const float*)d_in[5];
    const float* b4 = (const float*)d_in[6];
    const float* j_w = (const float*)d_in[7];
    const float* k_w = (const float*)d_in[8];
    float* out = (float*)d_out;

    const size_t stateB = (size_t)BB * 64 * sizeof(float2);  // 1 MB
    const size_t colGB  = (size_t)TT * 256 * 2 * 4;          // 1 MB
    const size_t w2hB   = (size_t)HH * HH * 2 * 2;           // 256 KB (hi+lo)
    const size_t statsB = 65536;
    int TC = 512;
    while (TC > 8 && ((size_t)TC * BB * HH * 4 + stateB + colGB + w2hB + statsB) > ws_size) TC >>= 1;
    int NC = TT / TC;

    char* w = (char*)d_ws;
    float* buf = (float*)w;
    size_t off = (size_t)TC * BB * HH * 4;
    float2* statep = (float2*)(w + off); off += stateB;
    unsigned* colGmn = (unsigned*)(w + off); off += colGB / 2;
    unsigned* colGmx = (unsigned*)(w + off); off += colGB / 2;
    _Float16* W2hi = (_Float16*)(w + off); off += w2hB / 2;
    _Float16* W2lo = (_Float16*)(w + off); off += w2hB / 2;
    float* fst = (float*)(w + off);
    float* mn1f = fst;        float* s1f = fst + 512;
    float* mn2f = fst + 1024; float* s2f = fst + 1536;
    float* mjf  = fst + 2048; float* sjf = fst + 2560;
    float* mkf  = fst + 3072; float* skf = fst + 3584;
    float* mn4f = fst + 4096; float* s4f = fst + 4608;
    float* out4p = out;  // (B,T) pre-activation lives in d_out, normalized in place

    k0_stats<<<512, 256, 0, stream>>>(X, W1, b1, mn1f, s1f, colGmn, colGmx, statep);
    k0b_cvt<<<64, 256, 0, stream>>>(W2, W2hi, W2lo);
    for (int c = 0; c < NC; ++c) {
        int tbase = c * TC;
        k1_gemm<<<dim3(BB / 64, 1, TC), 256, 0, stream>>>(X, W1, b1, W2hi, W2lo, b2, mn1f, s1f,
                                                          buf, colGmn, colGmx, tbase);
        k1b<<<TC, 256, 0, stream>>>(colGmn, colGmx, j_w, k_w, mn2f, s2f, mjf, sjf, mkf, skf, tbase);
        k3_scan<<<512, 256, 0, stream>>>(buf, W4, b4, mn2f, s2f, mjf, sjf, mkf, skf,
                                         j_w, k_w, statep, out4p, tbase, TC);
    }
    k3b<<<512, 256, 0, stream>>>(out4p, mn4f, s4f);
    k4_final<<<1024, 256, 0, stream>>>(out, mn4f, s4f);
}

// Round 7
// 973.915 us; speedup vs baseline: 1.2767x; 1.2546x over previous
//
#include <hip/hip_runtime.h>

#define TT 512
#define BB 2048
#define HH 256

typedef _Float16 f16x8 __attribute__((ext_vector_type(8)));
typedef _Float16 f16x4 __attribute__((ext_vector_type(4)));
typedef float f32x4 __attribute__((ext_vector_type(4)));

// fast sigmoid: v_exp + v_rcp (~1e-7 rel err; consistency k1b<->k3 is slope-bounded, safe)
__device__ __forceinline__ float sigf(float z) {
    return __builtin_amdgcn_rcpf(1.0f + __expf(-z));
}
// order-preserving float<->uint for atomic min/max
__device__ __forceinline__ unsigned f2o(float f) {
    unsigned u = __float_as_uint(f);
    return (u & 0x80000000u) ? ~u : (u | 0x80000000u);
}
__device__ __forceinline__ float o2f(unsigned o) {
    unsigned u = (o & 0x80000000u) ? (o & 0x7fffffffu) : ~o;
    return __uint_as_float(u);
}

// K0: per-t col min/max of X -> analytic out1 normalizer; init colG atomics + scan state.
__global__ __launch_bounds__(256) void k0_stats(const float* __restrict__ X,
                                                const float* __restrict__ W1,
                                                const float* __restrict__ b1,
                                                float* __restrict__ mn1f, float* __restrict__ s1f,
                                                unsigned* __restrict__ colGmn,
                                                unsigned* __restrict__ colGmx,
                                                float2* __restrict__ statep) {
    int t = blockIdx.x, tid = threadIdx.x;
    statep[blockIdx.x * 256 + tid] = make_float2(0.f, 0.f);  // ws never re-poisoned: re-init each launch
    colGmn[(size_t)t * 256 + tid] = 0xFFFFFFFFu;
    colGmx[(size_t)t * 256 + tid] = 0u;
    __shared__ float rmn[256], rmx[256];
    float mn = 3.4e38f, mx = -3.4e38f;
    for (int b = tid; b < BB; b += 256) {
        float v = X[(size_t)b * TT + t];
        mn = fminf(mn, v); mx = fmaxf(mx, v);
    }
    rmn[tid] = mn; rmx[tid] = mx; __syncthreads();
    for (int s = 128; s > 0; s >>= 1) {
        if (tid < s) { rmn[tid] = fminf(rmn[tid], rmn[tid + s]); rmx[tid] = fmaxf(rmx[tid], rmx[tid + s]); }
        __syncthreads();
    }
    float xmn = rmn[0], xmx = rmx[0];
    __syncthreads();
    float w = W1[tid], bb = b1[tid];
    float v0 = w * xmn + bb, v1 = w * xmx + bb;
    rmn[tid] = fminf(v0, v1); rmx[tid] = fmaxf(v0, v1); __syncthreads();
    for (int s = 128; s > 0; s >>= 1) {
        if (tid < s) { rmn[tid] = fminf(rmn[tid], rmn[tid + s]); rmx[tid] = fmaxf(rmx[tid], rmx[tid + s]); }
        __syncthreads();
    }
    if (tid == 0) {
        mn1f[t] = rmn[0];
        s1f[t] = 20.0f / (rmx[0] - rmn[0]);
    }
}

// K0b: W2 f32 -> f16 hi plane (A carries the split; B single-plane residual ~6e-5 pre-amp)
__global__ __launch_bounds__(256) void k0b_cvt(const float* __restrict__ W2,
                                               _Float16* __restrict__ W2hi) {
    int i4 = (blockIdx.x * 256 + threadIdx.x) * 4;
    float4 v = *(const float4*)&W2[i4];
    f16x4 h;
    h[0] = (_Float16)v.x; h[1] = (_Float16)v.y; h[2] = (_Float16)v.z; h[3] = (_Float16)v.w;
    *(f16x4*)&W2hi[i4] = h;
}

// K1: 2-MFMA split GEMM (alo*bh + ah*bh), tile 64 rows x 256 cols, 256 thr = 4 waves
// (each wave one 64-col slice, wave tile 64x64, acc 4x4).
// Full-K A panel (hi+lo) generated ONCE into exactly 64 KB LDS (granule-XOR swizzle),
// then a barrier-free K-loop: A from LDS, B direct from L2, loads pipeline across steps.
// Epilogue: col min/max via shfl + direct global atomics; C via LDS overlay, 1KB/instr stores.
__global__ __launch_bounds__(256) void k1_gemm(const float* __restrict__ X,
                                               const float* __restrict__ W1,
                                               const float* __restrict__ b1,
                                               const _Float16* __restrict__ W2h,
                                               const float* __restrict__ b2,
                                               const float* __restrict__ mn1f,
                                               const float* __restrict__ s1f,
                                               float* __restrict__ buf,
                                               unsigned* __restrict__ colGmn,
                                               unsigned* __restrict__ colGmx,
                                               int tbase) {
    int tl = blockIdx.z, t = tbase + tl;
    int bBase = blockIdx.x * 64;
    int tid = threadIdx.x;
    __shared__ __align__(16) _Float16 A[2][64 * 256];  // 65536 B; [plane][row*256 + swz_granule*8]
    float* C_lds = (float*)A;                          // overlay after compute ([64][256] f32)
    int lane = tid & 63, w = tid >> 6;
    int l15 = lane & 15, hi2 = lane >> 4;

    // ---- A generation: row sr = tid>>2, k-slice (tid&3)*64 .. +63
    {
        int sr = tid >> 2, ks0 = (tid & 3) * 64;
        float xr = X[(size_t)(bBase + sr) * TT + t];
        float mn1 = mn1f[t], s1 = s1f[t];
#pragma unroll
        for (int g = 0; g < 8; ++g) {
            int k = ks0 + g * 8;
            float4 wa = *(const float4*)&W1[k];
            float4 wb = *(const float4*)&W1[k + 4];
            float4 ba = *(const float4*)&b1[k];
            float4 bb = *(const float4*)&b1[k + 4];
            float av[8];
            av[0] = sigf((xr * wa.x + ba.x - mn1) * s1);
            av[1] = sigf((xr * wa.y + ba.y - mn1) * s1);
            av[2] = sigf((xr * wa.z + ba.z - mn1) * s1);
            av[3] = sigf((xr * wa.w + ba.w - mn1) * s1);
            av[4] = sigf((xr * wb.x + bb.x - mn1) * s1);
            av[5] = sigf((xr * wb.y + bb.y - mn1) * s1);
            av[6] = sigf((xr * wb.z + bb.z - mn1) * s1);
            av[7] = sigf((xr * wb.w + bb.w - mn1) * s1);
            f16x8 hv, lv;
#pragma unroll
            for (int u = 0; u < 8; ++u) {
                _Float16 ah = (_Float16)av[u];
                hv[u] = ah;
                lv[u] = (_Float16)(av[u] - (float)ah);
            }
            int kgs = (k >> 3) ^ (sr & 7);  // granule XOR swizzle (bijective per row)
            *(f16x8*)&A[0][sr * 256 + kgs * 8] = hv;
            *(f16x8*)&A[1][sr * 256 + kgs * 8] = lv;
        }
    }
    __syncthreads();  // the ONLY barrier before the K-loop

    // ---- barrier-free K-loop: 8 steps x {8 ds_read A, 4 global B, 32 MFMA}
    f32x4 acc[4][4];
#pragma unroll
    for (int i = 0; i < 4; ++i)
#pragma unroll
        for (int j = 0; j < 4; ++j) acc[i][j] = (f32x4)0.0f;

    const _Float16* bp[4];
#pragma unroll
    for (int j = 0; j < 4; ++j)
        bp[j] = W2h + (size_t)(w * 64 + j * 16 + l15) * HH + hi2 * 8;

#pragma unroll
    for (int s = 0; s < 8; ++s) {
        f16x8 bh[4];
#pragma unroll
        for (int j = 0; j < 4; ++j) bh[j] = *(const f16x8*)(bp[j] + s * 32);
#pragma unroll
        for (int i = 0; i < 4; ++i) {
            int row = i * 16 + l15;
            int kgs = (s * 4 + hi2) ^ (row & 7);
            f16x8 ah = *(const f16x8*)&A[0][row * 256 + kgs * 8];
            f16x8 al = *(const f16x8*)&A[1][row * 256 + kgs * 8];
#pragma unroll
            for (int j = 0; j < 4; ++j) {
                acc[i][j] = __builtin_amdgcn_mfma_f32_16x16x32_f16(al, bh[j], acc[i][j], 0, 0, 0);
                acc[i][j] = __builtin_amdgcn_mfma_f32_16x16x32_f16(ah, bh[j], acc[i][j], 0, 0, 0);
            }
        }
    }

    // ---- epilogue: +b2, per-col min/max -> direct global atomics (cols disjoint per wave)
    float b2r[4];
#pragma unroll
    for (int j = 0; j < 4; ++j) b2r[j] = b2[w * 64 + j * 16 + l15];
#pragma unroll
    for (int j = 0; j < 4; ++j) {
        float vmn = 3.4e38f, vmx = -3.4e38f;
#pragma unroll
        for (int i = 0; i < 4; ++i)
#pragma unroll
            for (int q = 0; q < 4; ++q) {
                float v = acc[i][j][q] + b2r[j];
                acc[i][j][q] = v;
                vmn = fminf(vmn, v); vmx = fmaxf(vmx, v);
            }
        vmn = fminf(vmn, __shfl_xor(vmn, 16)); vmn = fminf(vmn, __shfl_xor(vmn, 32));
        vmx = fmaxf(vmx, __shfl_xor(vmx, 16)); vmx = fmaxf(vmx, __shfl_xor(vmx, 32));
        if (hi2 == 0) {
            int c = w * 64 + j * 16 + l15;
            atomicMin(&colGmn[(size_t)t * 256 + c], f2o(vmn));
            atomicMax(&colGmx[(size_t)t * 256 + c], f2o(vmx));
        }
    }
    __syncthreads();  // A dead -> overlay C
#pragma unroll
    for (int i = 0; i < 4; ++i)
#pragma unroll
        for (int j = 0; j < 4; ++j)
#pragma unroll
            for (int q = 0; q < 4; ++q)
                C_lds[(i * 16 + hi2 * 4 + q) * 256 + w * 64 + j * 16 + l15] = acc[i][j][q];
    __syncthreads();
    // coalesced: each instr = 64 lanes x 16 B = one contiguous 1 KB row segment
#pragma unroll
    for (int it = 0; it < 16; ++it) {
        int idx = it * 256 + tid;
        int row = idx >> 6, g = idx & 63;
        float4 v = *(const float4*)&C_lds[row * 256 + g * 4];
        *(float4*)&buf[((size_t)tl * BB + bBase + row) * HH + g * 4] = v;
    }
}

// K1b: per-t analytic normalizers for out2 and (via sigmoid monotonicity) jpre/kpre.
__global__ __launch_bounds__(256) void k1b(const unsigned* __restrict__ colGmn,
                                           const unsigned* __restrict__ colGmx,
                                           const float* __restrict__ j_w,
                                           const float* __restrict__ k_w,
                                           float* __restrict__ mn2f, float* __restrict__ s2f,
                                           float* __restrict__ mjf, float* __restrict__ sjf,
                                           float* __restrict__ mkf, float* __restrict__ skf,
                                           int tbase) {
    int t = tbase + blockIdx.x, tid = threadIdx.x;
    __shared__ float ra[256], rb[256];
    float cmn = o2f(colGmn[(size_t)t * 256 + tid]);
    float cmx = o2f(colGmx[(size_t)t * 256 + tid]);
    ra[tid] = cmn; rb[tid] = cmx; __syncthreads();
    for (int s = 128; s > 0; s >>= 1) {
        if (tid < s) { ra[tid] = fminf(ra[tid], ra[tid + s]); rb[tid] = fmaxf(rb[tid], rb[tid + s]); }
        __syncthreads();
    }
    float mn2 = ra[0], mx2 = rb[0];
    float s2 = 20.0f / (mx2 - mn2);
    __syncthreads();
    // endpoint transform (exactly the scan's expression); j half = cols 0..127, k half = 128..255
    float wv = (tid < 128) ? j_w[tid] : k_w[tid - 128];
    float ea = sigf((cmn - mn2) * s2) * wv;
    float eb = sigf((cmx - mn2) * s2) * wv;
    ra[tid] = fminf(ea, eb); rb[tid] = fmaxf(ea, eb); __syncthreads();
    for (int s = 64; s > 0; s >>= 1) {
        if ((tid & 127) < s) { ra[tid] = fminf(ra[tid], ra[tid + s]); rb[tid] = fmaxf(rb[tid], rb[tid + s]); }
        __syncthreads();
    }
    if (tid == 0) {
        mn2f[t] = mn2; s2f[t] = s2;
        mjf[t] = ra[0]; sjf[t] = 20.0f / (rb[0] - ra[0]);
    }
    if (tid == 128) {
        mkf[t] = ra[128]; skf[t] = 20.0f / (rb[128] - ra[128]);
    }
}

// K3: affine scan; computes jpre/kpre + gates on the fly from out2_pre.
__global__ __launch_bounds__(256) void k3_scan(const float* __restrict__ buf,
                                               const float* __restrict__ W4,
                                               const float* __restrict__ b4,
                                               const float* __restrict__ mn2f, const float* __restrict__ s2f,
                                               const float* __restrict__ mjf, const float* __restrict__ sjf,
                                               const float* __restrict__ mkf, const float* __restrict__ skf,
                                               const float* __restrict__ j_w, const float* __restrict__ k_w,
                                               float2* __restrict__ statep,
                                               float* __restrict__ out4p,
                                               int tbase, int TC) {
    __shared__ float n2L[512], c2L[512], mjL[512], sjL[512], mkL[512], skL[512];
    int tid = threadIdx.x;
    for (int tl = tid; tl < TC; tl += 256) {
        int t = tbase + tl;
        n2L[tl] = mn2f[t]; c2L[tl] = s2f[t];
        mjL[tl] = mjf[t]; sjL[tl] = sjf[t];
        mkL[tl] = mkf[t]; skL[tl] = skf[t];
    }
    __syncthreads();
    int wave = tid >> 6, lane = tid & 63;
    int b = blockIdx.x * 4 + wave;
    float w40 = W4[2 * lane], w41 = W4[2 * lane + 1];
    float jw0 = j_w[2 * lane], jw1 = j_w[2 * lane + 1];
    float kw0 = k_w[2 * lane], kw1 = k_w[2 * lane + 1];
    float bb4 = b4[0];
    float2 stv = statep[b * 64 + lane];
    float s0 = stv.x, s1v = stv.y;
    const float2* basep = (const float2*)buf;
    const int rowstride = BB * 128;
    int off0 = b * 128 + lane;
    float rsave = 0.f;
    float2 jq[8], kq[8];
#pragma unroll
    for (int u = 0; u < 8; ++u) {
        jq[u] = basep[(size_t)u * rowstride + off0];
        kq[u] = basep[(size_t)u * rowstride + off0 + 64];
    }
    for (int t0 = 0; t0 < TC; t0 += 8) {
#pragma unroll
        for (int u = 0; u < 8; ++u) {
            int tl = t0 + u;
            float2 jp = jq[u], kp = kq[u];
            int tn = tl + 8;
            if (tn < TC) {
                jq[u] = basep[(size_t)tn * rowstride + off0];
                kq[u] = basep[(size_t)tn * rowstride + off0 + 64];
            }
            float n2 = n2L[tl], c2 = c2L[tl];
            float pj0 = sigf((jp.x - n2) * c2) * jw0;
            float pj1 = sigf((jp.y - n2) * c2) * jw1;
            float pk0 = sigf((kp.x - n2) * c2) * kw0;
            float pk1 = sigf((kp.y - n2) * c2) * kw1;
            float ij0 = sigf((pj0 - mjL[tl]) * sjL[tl]);
            float ij1 = sigf((pj1 - mjL[tl]) * sjL[tl]);
            float ik0 = sigf((pk0 - mkL[tl]) * skL[tl]);
            float ik1 = sigf((pk1 - mkL[tl]) * skL[tl]);
            s0 = ij0 + s0 * (1.0f - ij0 - ik0);
            s1v = ij1 + s1v * (1.0f - ij1 - ik1);
            float r = s0 * w40 + s1v * w41;
#pragma unroll
            for (int m = 1; m < 64; m <<= 1) r += __shfl_xor(r, m);
            if (lane == (tl & 63)) rsave = r + bb4;
        }
        if (((t0 + 8) & 63) == 0) {  // coalesced 64-step flush
            int base = t0 + 8 - 64;
            out4p[(size_t)b * TT + tbase + base + lane] = rsave;
        }
    }
    if (TC < 64 && lane < TC) out4p[(size_t)b * TT + tbase + lane] = rsave;
    statep[b * 64 + lane] = make_float2(s0, s1v);
}

__global__ __launch_bounds__(256) void k3b(const float* __restrict__ out4p,
                                           float* __restrict__ mn4f, float* __restrict__ s4f) {
    int t = blockIdx.x, tid = threadIdx.x;
    __shared__ float rmn[256], rmx[256];
    float mn = 3.4e38f, mx = -3.4e38f;
    for (int b = tid; b < BB; b += 256) {
        float v = out4p[(size_t)b * TT + t];
        mn = fminf(mn, v); mx = fmaxf(mx, v);
    }
    rmn[tid] = mn; rmx[tid] = mx; __syncthreads();
    for (int s = 128; s > 0; s >>= 1) {
        if (tid < s) { rmn[tid] = fminf(rmn[tid], rmn[tid + s]); rmx[tid] = fmaxf(rmx[tid], rmx[tid + s]); }
        __syncthreads();
    }
    if (tid == 0) { mn4f[t] = rmn[0]; s4f[t] = 20.0f / (rmx[0] - rmn[0]); }
}

__global__ __launch_bounds__(256) void k4_final(float* __restrict__ out,
                                                const float* __restrict__ mn4f,
                                                const float* __restrict__ s4f) {
    int i = blockIdx.x * 256 + threadIdx.x;
    float4 v = ((const float4*)out)[i];
    int t0 = (i * 4) & (TT - 1);
    float4 mn = *(const float4*)&mn4f[t0];
    float4 sc = *(const float4*)&s4f[t0];
    float4 r;
    r.x = sigf((v.x - mn.x) * sc.x);
    r.y = sigf((v.y - mn.y) * sc.y);
    r.z = sigf((v.z - mn.z) * sc.z);
    r.w = sigf((v.w - mn.w) * sc.w);
    ((float4*)out)[i] = r;
}

extern "C" void kernel_launch(void* const* d_in, const int* in_sizes, int n_in,
                              void* d_out, int out_size, void* d_ws, size_t ws_size,
                              hipStream_t stream) {
    const float* X  = (const float*)d_in[0];
    const float* W1 = (const float*)d_in[1];
    const float* b1 = (const float*)d_in[2];
    const float* W2 = (const float*)d_in[3];
    const float* b2 = (const float*)d_in[4];
    const float* W4 = (const float*)d_in[5];
    const float* b4 = (const float*)d_in[6];
    const float* j_w = (const float*)d_in[7];
    const float* k_w = (const float*)d_in[8];
    float* out = (float*)d_out;

    const size_t stateB = (size_t)BB * 64 * sizeof(float2);  // 1 MB
    const size_t colGB  = (size_t)TT * 256 * 2 * 4;          // 1 MB
    const size_t w2hB   = (size_t)HH * HH * 2;               // 128 KB (hi only)
    const size_t statsB = 65536;
    int TC = 512;
    while (TC > 8 && ((size_t)TC * BB * HH * 4 + stateB + colGB + w2hB + statsB) > ws_size) TC >>= 1;
    int NC = TT / TC;

    char* w = (char*)d_ws;
    float* buf = (float*)w;
    size_t off = (size_t)TC * BB * HH * 4;
    float2* statep = (float2*)(w + off); off += stateB;
    unsigned* colGmn = (unsigned*)(w + off); off += colGB / 2;
    unsigned* colGmx = (unsigned*)(w + off); off += colGB / 2;
    _Float16* W2hi = (_Float16*)(w + off); off += w2hB;
    float* fst = (float*)(w + off);
    float* mn1f = fst;        float* s1f = fst + 512;
    float* mn2f = fst + 1024; float* s2f = fst + 1536;
    float* mjf  = fst + 2048; float* sjf = fst + 2560;
    float* mkf  = fst + 3072; float* skf = fst + 3584;
    float* mn4f = fst + 4096; float* s4f = fst + 4608;
    float* out4p = out;  // (B,T) pre-activation lives in d_out, normalized in place

    k0_stats<<<512, 256, 0, stream>>>(X, W1, b1, mn1f, s1f, colGmn, colGmx, statep);
    k0b_cvt<<<64, 256, 0, stream>>>(W2, W2hi);
    for (int c = 0; c < NC; ++c) {
        int tbase = c * TC;
        k1_gemm<<<dim3(BB / 64, 1, TC), 256, 0, stream>>>(X, W1, b1, W2hi, b2, mn1f, s1f,
                                                          buf, colGmn, colGmx, tbase);
        k1b<<<TC, 256, 0, stream>>>(colGmn, colGmx, j_w, k_w, mn2f, s2f, mjf, sjf, mkf, skf, tbase);
        k3_scan<<<512, 256, 0, stream>>>(buf, W4, b4, mn2f, s2f, mjf, sjf, mkf, skf,
                                         j_w, k_w, statep, out4p, tbase, TC);
    }
    k3b<<<512, 256, 0, stream>>>(out4p, mn4f, s4f);
    k4_final<<<1024, 256, 0, stream>>>(out, mn4f, s4f);
}